// Round 8
// baseline (219.162 us; speedup 1.0000x reference)
//
#include <hip/hip_runtime.h>
#include <hip/hip_bf16.h>
#include <stdint.h>

typedef __attribute__((ext_vector_type(8))) short short8;
typedef __attribute__((ext_vector_type(4))) float f32x4;
typedef __attribute__((ext_vector_type(16))) float f32x16;
typedef const __attribute__((address_space(1))) uint32_t* gas1_t;
typedef __attribute__((address_space(3))) uint32_t* las3_t;

__device__ __forceinline__ short f2bf(float f) {
  uint32_t u = __builtin_bit_cast(uint32_t, f);
  u += 0x7fffu + ((u >> 16) & 1u);
  return (short)(u >> 16);
}
__device__ __forceinline__ float bf2f(short s) {
  return __builtin_bit_cast(float, ((uint32_t)(uint16_t)s) << 16);
}

// ---- convert q,k,v f32 -> bf16 (z selects tensor) ----
__global__ __launch_bounds__(256) void cvt_qkv_k(const float* __restrict__ q,
    const float* __restrict__ k, const float* __restrict__ v,
    short* __restrict__ dst) {
  const long long n = 8388608LL;
  const float* src = (blockIdx.z == 0) ? q : (blockIdx.z == 1) ? k : v;
  long long i = ((long long)blockIdx.x * 256 + threadIdx.x) * 8;
  float4 a = *(const float4*)(src + i);
  float4 b = *(const float4*)(src + i + 4);
  short8 o;
  o[0]=f2bf(a.x); o[1]=f2bf(a.y); o[2]=f2bf(a.z); o[3]=f2bf(a.w);
  o[4]=f2bf(b.x); o[5]=f2bf(b.y); o[6]=f2bf(b.z); o[7]=f2bf(b.w);
  *(short8*)(dst + (long long)blockIdx.z * n + i) = o;
}

// ---- gather the 4 bias vectors into one contiguous buffer ----
__global__ __launch_bounds__(256) void bias_gather_k(const float* b0, const float* b1,
    const float* b2, const float* b3, float* __restrict__ dst) {
  int i = blockIdx.x * 256 + threadIdx.x;
  if (i >= 4096) return;
  int z = i >> 10, j = i & 1023;
  const float* s = (z==0)?b0:(z==1)?b1:(z==2)?b2:b3;
  dst[i] = s[j];
}

// ---- weights: W[K=1024,N=1024] f32 -> Wt[N,K] bf16 (z selects weight) ----
__global__ __launch_bounds__(256) void wt_cvt_k(const float* w0, const float* w1,
    const float* w2, const float* w3, short* __restrict__ dst) {
  __shared__ float t[32][33];
  const float* W = (blockIdx.z==0)?w0:(blockIdx.z==1)?w1:(blockIdx.z==2)?w2:w3;
  short* D = dst + (long long)blockIdx.z * 1048576LL;
  int n0 = blockIdx.x * 32, k0 = blockIdx.y * 32;
  int tx = threadIdx.x, ty = threadIdx.y;
  #pragma unroll
  for (int i = 0; i < 4; ++i)
    t[ty + 8*i][tx] = W[(long long)(k0 + ty + 8*i) * 1024 + n0 + tx];
  __syncthreads();
  #pragma unroll
  for (int i = 0; i < 4; ++i)
    D[(long long)(n0 + ty + 8*i) * 1024 + k0 + tx] = f2bf(t[tx][ty + 8*i]);
}

// ---- in-place row softmax on bf16 [rows,2048] ----
__global__ __launch_bounds__(256) void softmax_bf_k(short* __restrict__ SP) {
  short* sp = SP + (long long)blockIdx.x * 2048;
  const int t = threadIdx.x;
  short8 sv = *(const short8*)(sp + t*8);
  float v[8];
  #pragma unroll
  for (int j = 0; j < 8; ++j) v[j] = bf2f(sv[j]);
  float m = v[0];
  #pragma unroll
  for (int j = 1; j < 8; ++j) m = fmaxf(m, v[j]);
  #pragma unroll
  for (int off = 32; off > 0; off >>= 1) m = fmaxf(m, __shfl_down(m, off, 64));
  __shared__ float rmax[4], rsum[4];
  int wv = t >> 6, ln = t & 63;
  if (ln == 0) rmax[wv] = m;
  __syncthreads();
  m = fmaxf(fmaxf(rmax[0], rmax[1]), fmaxf(rmax[2], rmax[3]));
  float e[8], sum = 0.f;
  #pragma unroll
  for (int j = 0; j < 8; ++j) { e[j] = exp2f((v[j] - m) * 1.44269504f); sum += e[j]; }
  #pragma unroll
  for (int off = 32; off > 0; off >>= 1) sum += __shfl_down(sum, off, 64);
  if (ln == 0) rsum[wv] = sum;
  __syncthreads();
  float inv = 1.0f / (rsum[0] + rsum[1] + rsum[2] + rsum[3]);
  short8 o;
  #pragma unroll
  for (int j = 0; j < 8; ++j) o[j] = f2bf(e[j] * inv);
  *(short8*)(sp + t*8) = o;
}

#define MFMA16(d, a_, b_) d = __builtin_amdgcn_mfma_f32_16x16x32_bf16(a_, b_, d, 0, 0, 0)
#define MFMA32(d, a_, b_) d = __builtin_amdgcn_mfma_f32_32x32x16_bf16(a_, b_, d, 0, 0, 0)
#define LGKM0 do { asm volatile("s_waitcnt lgkmcnt(0)" ::: "memory"); \
                   __builtin_amdgcn_sched_barrier(0); } while (0)
// flattened 1-D grid + bijective XCD-chunked swizzle (nwg % 8 == 0 at all call sites)
#define XCD_DECODE(gxs_, gys_) \
  const int nwg = (int)gridDim.x; \
  const int wg = ((int)blockIdx.x & 7) * (nwg >> 3) + ((int)blockIdx.x >> 3); \
  const int bxi = wg & ((1 << (gxs_)) - 1); \
  const int byi = (wg >> (gxs_)) & ((1 << (gys_)) - 1); \
  const int z = wg >> ((gxs_) + (gys_));

// ============================================================================
// gemm4h: 256x128 GEMM, BK=32, LDS 72 KB -> 2 blocks/CU (4 waves/SIMD).
// Co-residency experiment: same AI (85 F/B) and fat 16-MFMA cluster as the
// proven R4 ring, but two independent blocks per CU interleave their
// lgkm/barrier/load stalls. 3-buffer ring, stage-distance 2, 1 barrier/tile.
// Per tile/wave: 8 ds_read_b128 + 16 MFMA16. 3 STGs/tile (A 2x128rows, B 1).
// vmcnt: prologue 6 issued, wait vmcnt(3) = tile0 landed; steady: outstanding
// 6 (tiles g+1,g+2), vmcnt(3) drains tile g+1; tail vmcnt(0).
// Swizzle (4 granules/row): read g = lk ^ ((lr>>1)&3) -> bank slots
// (row&1, g) = 8 slots x 2 lanes = conflict-free; stage source granule
// (lane&3) ^ ((lane>>3)&3) is the same involution (linear gload_lds dest).
// ============================================================================
template<int OUT_BF16>
__global__ __launch_bounds__(512, 4) void gemm4h_k(const short* __restrict__ A,
    const short* __restrict__ Bt, void* __restrict__ Cv,
    const float* __restrict__ bias,
    int K, int lda, int ldb, int ldc,
    long long sA, long long sB, long long sC, long long sBias,
    float scale, int gxs, int gys)
{
  __shared__ __align__(16) short lds[3][12288];  // per buf: A [0,8192) B [8192,12288)
  XCD_DECODE(gxs, gys);
  A  += (long long)z * sA;
  Bt += (long long)z * sB;
  const int bm = byi * 256;
  const int bn = bxi * 128;
  const int tid  = threadIdx.x;
  const int w    = tid >> 6, lane = tid & 63;
  const int wr   = w >> 1,   wc   = w & 1;     // (WM,WN) = (4,2): per-wave 64x64
  const int lr   = lane & 15, lk  = lane >> 4;

  const int rsw  = (lk ^ ((lr >> 1) & 3)) * 8;           // read granule (shorts)
  const int srow = w * 16 + (lane >> 2);                 // 0..127 within region
  const int sg   = ((lane & 3) ^ ((lane >> 3) & 3)) * 8; // stage source granule
  const short* gA[2]; const short* gB;
  #pragma unroll
  for (int h = 0; h < 2; ++h)
    gA[h] = A + (long long)(bm + h*128 + srow) * lda + sg;
  gB = Bt + (long long)(bn + srow) * ldb + sg;

  #define STGAh(buf, h, kt) \
    __builtin_amdgcn_global_load_lds((gas1_t)(gA[h] + (long long)(kt)*32), \
        (las3_t)&lds[buf][(h)*4096 + w*512], 16, 0, 0)
  #define STGBh(buf, kt) \
    __builtin_amdgcn_global_load_lds((gas1_t)(gB + (long long)(kt)*32), \
        (las3_t)&lds[buf][8192 + w*512], 16, 0, 0)
  #define RDAh(buf, mi) (*(const short8*)&lds[buf][(wr*64 + (mi)*16 + lr)*32 + rsw])
  #define RDBh(buf, ni) (*(const short8*)&lds[buf][8192 + (wc*64 + (ni)*16 + lr)*32 + rsw])

  f32x4 acc[4][4] = {};
  const int nt = K >> 5;

  // prologue: tile0 -> buf0, tile1 -> buf1
  STGAh(0, 0, 0); STGAh(0, 1, 0); STGBh(0, 0);
  STGAh(1, 0, 1); STGAh(1, 1, 1); STGBh(1, 1);
  asm volatile("s_waitcnt vmcnt(3)" ::: "memory");
  __builtin_amdgcn_s_barrier();

  int b = 0, nb = 2;
  for (int g = 0; g < nt; ++g) {
    short8 aR[4], bR[4];
    #pragma unroll
    for (int mi = 0; mi < 4; ++mi) aR[mi] = RDAh(b, mi);
    #pragma unroll
    for (int ni = 0; ni < 4; ++ni) bR[ni] = RDBh(b, ni);
    if (g + 2 < nt) { STGAh(nb, 0, g+2); STGAh(nb, 1, g+2); STGBh(nb, g+2); }
    LGKM0;
    __builtin_amdgcn_s_setprio(1);
    #pragma unroll
    for (int mi = 0; mi < 4; ++mi)
      #pragma unroll
      for (int ni = 0; ni < 4; ++ni)
        MFMA16(acc[mi][ni], aR[mi], bR[ni]);
    __builtin_amdgcn_s_setprio(0);
    if (g + 2 < nt)      asm volatile("s_waitcnt vmcnt(3)" ::: "memory");
    else if (g + 1 < nt) asm volatile("s_waitcnt vmcnt(0)" ::: "memory");
    __builtin_amdgcn_s_barrier();
    b  = (b  == 2) ? 0 : b  + 1;
    nb = (nb == 2) ? 0 : nb + 1;
  }

  const float* bz = bias ? (bias + (long long)z * sBias) : nullptr;
  #pragma unroll
  for (int mi = 0; mi < 4; ++mi) {
    const int row = bm + wr*64 + mi*16 + lk*4;
    #pragma unroll
    for (int ni = 0; ni < 4; ++ni) {
      const int col = bn + wc*64 + ni*16 + lr;
      const float bval = bz ? bz[col] : 0.f;
      #pragma unroll
      for (int r = 0; r < 4; ++r) {
        float val = acc[mi][ni][r] * scale + bval;
        if (OUT_BF16)
          ((short*)Cv)[(long long)z*sC + (long long)(row + r) * ldc + col] = f2bf(val);
        else
          ((float*)Cv)[(long long)z*sC + (long long)(row + r) * ldc + col] = val;
      }
    }
  }
  #undef STGAh
  #undef STGBh
  #undef RDAh
  #undef RDBh
}

// ============================================================================
// 256x128 GEMM, BK=64, 3-buffer ring (144 KB, 1 block/CU), 32x32x16 MFMA.
// Proven R4/R6 template — used where the grid can't fill 512 blocks.
// ============================================================================
template<int OUT_BF16, int BIAS_ROW>
__global__ __launch_bounds__(512, 2) void gemm4_k(const short* __restrict__ A,
    const short* __restrict__ Bt, void* __restrict__ Cv,
    const float* __restrict__ bias,
    int K, int lda, int ldb, int ldc,
    long long sA, long long sB, long long sC, long long sBias,
    float scale, int gxs, int gys)
{
  __shared__ __align__(16) short lds[3][24576];  // per buf: A [0,16384) B [16384,24576)
  XCD_DECODE(gxs, gys);
  A  += (long long)z * sA;
  Bt += (long long)z * sB;
  const int bm = byi * 256;
  const int bn = bxi * 128;
  const int tid  = threadIdx.x;
  const int w    = tid >> 6, lane = tid & 63;
  const int wr   = w >> 1,   wc   = w & 1;
  const int l31  = lane & 31, l5 = lane >> 5, rq = lane & 7;

  const int srow = w * 8 + (lane >> 3);
  const int swc  = ((lane & 7) ^ ((lane >> 3) & 7)) * 8;
  const short* gA[4]; const short* gB[2];
  #pragma unroll
  for (int i = 0; i < 4; ++i)
    gA[i] = A + (long long)(bm + i*64 + srow) * lda + swc;
  #pragma unroll
  for (int i = 0; i < 2; ++i)
    gB[i] = Bt + (long long)(bn + i*64 + srow) * ldb + swc;

  #define STGA(buf, i, kt) \
    __builtin_amdgcn_global_load_lds((gas1_t)(gA[i] + (long long)(kt)*64), \
        (las3_t)&lds[buf][(i)*4096 + w*512], 16, 0, 0)
  #define STGB(buf, i, kt) \
    __builtin_amdgcn_global_load_lds((gas1_t)(gB[i] + (long long)(kt)*64), \
        (las3_t)&lds[buf][16384 + (i)*4096 + w*512], 16, 0, 0)
  #define RDA32(buf, mi, ks) (*(const short8*)&lds[buf][(wr*64 + (mi)*32 + l31)*64 + ((((ks)*2 + l5) ^ rq))*8])
  #define RDB32(buf, ni, ks) (*(const short8*)&lds[buf][16384 + (wc*64 + (ni)*32 + l31)*64 + ((((ks)*2 + l5) ^ rq))*8])

  f32x16 acc[2][2] = {};
  const int nt = K >> 6;

  STGA(0, 0, 0); STGA(0, 2, 0); STGB(0, 0, 0);
  STGB(0, 1, 0); STGA(0, 1, 0); STGA(0, 3, 0);
  STGA(1, 0, 1); STGA(1, 2, 1); STGB(1, 0, 1);
  STGB(1, 1, 1); STGA(1, 1, 1); STGA(1, 3, 1);
  asm volatile("s_waitcnt vmcnt(6)" ::: "memory");
  __builtin_amdgcn_s_barrier();

  int b = 0, nb = 2;
  for (int g = 0; g < nt; ++g) {
    short8 aR[2][2], bR[2][2];
    // ---- half 1: ks = 0,1 ----
    #pragma unroll
    for (int mi = 0; mi < 2; ++mi) { aR[mi][0] = RDA32(b, mi, 0); aR[mi][1] = RDA32(b, mi, 1); }
    #pragma unroll
    for (int ni = 0; ni < 2; ++ni) { bR[ni][0] = RDB32(b, ni, 0); bR[ni][1] = RDB32(b, ni, 1); }
    if (g + 2 < nt) { STGA(nb, 0, g+2); STGA(nb, 2, g+2); STGB(nb, 0, g+2); }
    LGKM0;
    __builtin_amdgcn_s_setprio(1);
    #pragma unroll
    for (int mi = 0; mi < 2; ++mi)
      #pragma unroll
      for (int ni = 0; ni < 2; ++ni) {
        MFMA32(acc[mi][ni], aR[mi][0], bR[ni][0]);
        MFMA32(acc[mi][ni], aR[mi][1], bR[ni][1]);
      }
    __builtin_amdgcn_s_setprio(0);
    // ---- half 2: ks = 2,3 ----
    #pragma unroll
    for (int mi = 0; mi < 2; ++mi) { aR[mi][0] = RDA32(b, mi, 2); aR[mi][1] = RDA32(b, mi, 3); }
    #pragma unroll
    for (int ni = 0; ni < 2; ++ni) { bR[ni][0] = RDB32(b, ni, 2); bR[ni][1] = RDB32(b, ni, 3); }
    if (g + 2 < nt) { STGB(nb, 1, g+2); STGA(nb, 1, g+2); STGA(nb, 3, g+2); }
    LGKM0;
    __builtin_amdgcn_s_setprio(1);
    #pragma unroll
    for (int mi = 0; mi < 2; ++mi)
      #pragma unroll
      for (int ni = 0; ni < 2; ++ni) {
        MFMA32(acc[mi][ni], aR[mi][0], bR[ni][0]);
        MFMA32(acc[mi][ni], aR[mi][1], bR[ni][1]);
      }
    __builtin_amdgcn_s_setprio(0);
    if (g + 2 < nt)      asm volatile("s_waitcnt vmcnt(6)" ::: "memory");
    else if (g + 1 < nt) asm volatile("s_waitcnt vmcnt(0)" ::: "memory");
    __builtin_amdgcn_s_barrier();
    b  = (b  == 2) ? 0 : b  + 1;
    nb = (nb == 2) ? 0 : nb + 1;
  }

  const float* bz = bias;
  #pragma unroll
  for (int mi = 0; mi < 2; ++mi) {
    #pragma unroll
    for (int ni = 0; ni < 2; ++ni) {
      const int col = bn + wc*64 + ni*32 + l31;
      const float bcol = (bz && !BIAS_ROW) ? bz[(long long)z*sBias + col] : 0.f;
      #pragma unroll
      for (int r = 0; r < 16; ++r) {
        const int row = bm + wr*64 + mi*32 + (r&3) + 8*(r>>2) + 4*l5;
        float bval = BIAS_ROW ? bz[row] : bcol;
        float val = acc[mi][ni][r] * scale + bval;
        if (OUT_BF16)
          ((short*)Cv)[(long long)z*sC + (long long)row * ldc + col] = f2bf(val);
        else
          ((float*)Cv)[(long long)z*sC + (long long)row * ldc + col] = val;
      }
    }
  }
  #undef STGA
  #undef STGB
  #undef RDA32
  #undef RDB32
}

extern "C" void kernel_launch(void* const* d_in, const int* in_sizes, int n_in,
                              void* d_out, int out_size, void* d_ws, size_t ws_size,
                              hipStream_t stream) {
  const float* q  = (const float*)d_in[0];
  const float* k  = (const float*)d_in[1];
  const float* v  = (const float*)d_in[2];
  const float* Wq = (const float*)d_in[4];
  const float* bq = (const float*)d_in[5];
  const float* Wk = (const float*)d_in[6];
  const float* bk = (const float*)d_in[7];
  const float* Wv = (const float*)d_in[8];
  const float* bv = (const float*)d_in[9];
  const float* Wo = (const float*)d_in[10];
  const float* bo = (const float*)d_in[11];

  // ws layout (bytes), R6 layout:
  char* w = (char*)d_ws;
  short* Wt     = (short*)(w);                  // [4][1024][1024] bf16 (W^T)   8,388,608
  float* biasb  = (float*)(w + 8388608);        // [4][1024] f32                   16,384
  short* QKV    = (short*)(w + 8404992);        // Q,K bf16 [2][4,2048,1024]
  short* qkvbf  = (short*)(w + 58736640);       // q,k,v bf16, die after projections
  short* P      = (short*)(w + 58736640);       // scores/P bf16 [4,2048,2048] (reuses q,k part)
  short* Vt     = (short*)(w + 109068288);      // [1024][8192] bf16            16,777,216
  short* xt     = (short*)(w + 125845504);      // [4][1024][2048] bf16         16,777,216

  short* Qp = QKV;
  short* Kp = QKV + 8388608LL;
  short* vbf = qkvbf + 16777216LL;              // outside P's live range

  // 1) convert inputs + weights, gather biases
  cvt_qkv_k<<<dim3(4096,1,3), 256, 0, stream>>>(q, k, v, qkvbf);
  bias_gather_k<<<dim3(16), 256, 0, stream>>>(bq, bk, bv, bo, biasb);
  wt_cvt_k<<<dim3(32,32,4), dim3(32,8), 0, stream>>>(Wq, Wk, Wv, Wo, Wt);

  // 2a) q,k projections via gemm4h: 8(N) x 32(M) x 2(z) = 512 blocks, 2/CU
  gemm4h_k<1><<<512, 512, 0, stream>>>(qkvbf, Wt, QKV, biasb,
      1024, 1024, 1024, 1024, 8388608LL, 1048576LL, 8388608LL, 1024LL, 1.0f, 3, 5);

  // 2b) V projection, transposed output: Vt[d, bs] = Wv^T @ v_bf^T + bv[d]
  gemm4_k<1,1><<<256, 512, 0, stream>>>(Wt + 2097152LL, vbf, Vt, biasb + 2048,
      1024, 1024, 1024, 8192, 0LL, 0LL, 0LL, 0LL, 1.0f, 6, 2);

  // 3) scores = Q @ K^T / 32 -> bf16 P via gemm4h: 16(N) x 8(M) x 4(z) = 512
  gemm4h_k<1><<<512, 512, 0, stream>>>(Qp, Kp, P, nullptr,
      1024, 1024, 1024, 2048, 2097152LL, 2097152LL, 4194304LL, 0LL, 0.03125f, 4, 3);

  // 4) P = softmax_rows(P) in place
  softmax_bf_k<<<dim3(8192), 256, 0, stream>>>(P);

  // 5) xt[d, q] = Vt[d,:] . P[q,:]  (A = Vt + z*2048 cols, lda=8192)
  gemm4_k<1,0><<<256, 512, 0, stream>>>(Vt, P, xt, nullptr,
      2048, 8192, 2048, 2048, 2048LL, 4194304LL, 2097152LL, 0LL, 1.0f, 4, 2);

  // 6) out = reshape(xt) @ Wo + bo; xt reinterpreted [2048][1024] row-major per z
  gemm4_k<0,0><<<256, 512, 0, stream>>>(xt, Wt + 3145728LL, (float*)d_out,
      biasb + 3072, 1024, 1024, 1024, 1024, 2097152LL, 0LL, 2097152LL, 0LL, 1.0f, 3, 3);
}

// Round 9
// 205.911 us; speedup vs baseline: 1.0644x; 1.0644x over previous
//
#include <hip/hip_runtime.h>
#include <hip/hip_bf16.h>
#include <stdint.h>

typedef __attribute__((ext_vector_type(8))) short short8;
typedef __attribute__((ext_vector_type(4))) float f32x4;
typedef const __attribute__((address_space(1))) uint32_t* gas1_t;
typedef __attribute__((address_space(3))) uint32_t* las3_t;

__device__ __forceinline__ short f2bf(float f) {
  uint32_t u = __builtin_bit_cast(uint32_t, f);
  u += 0x7fffu + ((u >> 16) & 1u);
  return (short)(u >> 16);
}
__device__ __forceinline__ float bf2f(short s) {
  return __builtin_bit_cast(float, ((uint32_t)(uint16_t)s) << 16);
}

// ---- convert q,k,v f32 -> bf16 (z selects tensor) ----
__global__ __launch_bounds__(256) void cvt_qkv_k(const float* __restrict__ q,
    const float* __restrict__ k, const float* __restrict__ v,
    short* __restrict__ dst) {
  const long long n = 8388608LL;
  const float* src = (blockIdx.z == 0) ? q : (blockIdx.z == 1) ? k : v;
  long long i = ((long long)blockIdx.x * 256 + threadIdx.x) * 8;
  float4 a = *(const float4*)(src + i);
  float4 b = *(const float4*)(src + i + 4);
  short8 o;
  o[0]=f2bf(a.x); o[1]=f2bf(a.y); o[2]=f2bf(a.z); o[3]=f2bf(a.w);
  o[4]=f2bf(b.x); o[5]=f2bf(b.y); o[6]=f2bf(b.z); o[7]=f2bf(b.w);
  *(short8*)(dst + (long long)blockIdx.z * n + i) = o;
}

// ---- gather the 4 bias vectors into one contiguous buffer ----
__global__ __launch_bounds__(256) void bias_gather_k(const float* b0, const float* b1,
    const float* b2, const float* b3, float* __restrict__ dst) {
  int i = blockIdx.x * 256 + threadIdx.x;
  if (i >= 4096) return;
  int z = i >> 10, j = i & 1023;
  const float* s = (z==0)?b0:(z==1)?b1:(z==2)?b2:b3;
  dst[i] = s[j];
}

// ---- weights: W[K=1024,N=1024] f32 -> Wt[N,K] bf16 (z selects weight) ----
__global__ __launch_bounds__(256) void wt_cvt_k(const float* w0, const float* w1,
    const float* w2, const float* w3, short* __restrict__ dst) {
  __shared__ float t[32][33];
  const float* W = (blockIdx.z==0)?w0:(blockIdx.z==1)?w1:(blockIdx.z==2)?w2:w3;
  short* D = dst + (long long)blockIdx.z * 1048576LL;
  int n0 = blockIdx.x * 32, k0 = blockIdx.y * 32;
  int tx = threadIdx.x, ty = threadIdx.y;
  #pragma unroll
  for (int i = 0; i < 4; ++i)
    t[ty + 8*i][tx] = W[(long long)(k0 + ty + 8*i) * 1024 + n0 + tx];
  __syncthreads();
  #pragma unroll
  for (int i = 0; i < 4; ++i)
    D[(long long)(n0 + ty + 8*i) * 1024 + k0 + tx] = f2bf(t[tx][ty + 8*i]);
}

// ---- in-place row softmax on bf16 [rows,2048] ----
__global__ __launch_bounds__(256) void softmax_bf_k(short* __restrict__ SP) {
  short* sp = SP + (long long)blockIdx.x * 2048;
  const int t = threadIdx.x;
  short8 sv = *(const short8*)(sp + t*8);
  float v[8];
  #pragma unroll
  for (int j = 0; j < 8; ++j) v[j] = bf2f(sv[j]);
  float m = v[0];
  #pragma unroll
  for (int j = 1; j < 8; ++j) m = fmaxf(m, v[j]);
  #pragma unroll
  for (int off = 32; off > 0; off >>= 1) m = fmaxf(m, __shfl_down(m, off, 64));
  __shared__ float rmax[4], rsum[4];
  int wv = t >> 6, ln = t & 63;
  if (ln == 0) rmax[wv] = m;
  __syncthreads();
  m = fmaxf(fmaxf(rmax[0], rmax[1]), fmaxf(rmax[2], rmax[3]));
  float e[8], sum = 0.f;
  #pragma unroll
  for (int j = 0; j < 8; ++j) { e[j] = exp2f((v[j] - m) * 1.44269504f); sum += e[j]; }
  #pragma unroll
  for (int off = 32; off > 0; off >>= 1) sum += __shfl_down(sum, off, 64);
  if (ln == 0) rsum[wv] = sum;
  __syncthreads();
  float inv = 1.0f / (rsum[0] + rsum[1] + rsum[2] + rsum[3]);
  short8 o;
  #pragma unroll
  for (int j = 0; j < 8; ++j) o[j] = f2bf(e[j] * inv);
  *(short8*)(sp + t*8) = o;
}

#define MFMA16(d, a_, b_) d = __builtin_amdgcn_mfma_f32_16x16x32_bf16(a_, b_, d, 0, 0, 0)
#define LGKM0 do { asm volatile("s_waitcnt lgkmcnt(0)" ::: "memory"); \
                   __builtin_amdgcn_sched_barrier(0); } while (0)
// flattened 1-D grid + bijective XCD-chunked swizzle (nwg % 8 == 0 at all call sites)
#define XCD_DECODE(gxs_, gys_) \
  const int nwg = (int)gridDim.x; \
  const int wg = ((int)blockIdx.x & 7) * (nwg >> 3) + ((int)blockIdx.x >> 3); \
  const int bxi = wg & ((1 << (gxs_)) - 1); \
  const int byi = (wg >> (gxs_)) & ((1 << (gys_)) - 1); \
  const int z = wg >> ((gxs_) + (gys_));

// ============================================================================
// gemm2: 256x256 tile, BK=32, 3-buffer ring (96 KB), ONE barrier per K-tile,
// 8 waves (2M x 4N) -> per-wave 128x64 out (best LDS:MFMA ratio, 1/42.7).
// Per tile per wave: 12 ds_read_b128 + 32 MFMA16 in two 16-MFMA half-phases
// (caps live VGPR ~200). Staging: 4 STGs/tile (A 2x128rows, B 2x128rows),
// ring distance 2; vmcnt: prologue 8 issued -> vmcnt(4) = tile0 landed;
// steady: issue 4 (tile g+2) -> 8 outstanding -> vmcnt(4) drains tile g+1;
// tail vmcnt(0). Swizzle = gemm4h's measured-conflict-free pair:
// read granule lk ^ ((lr>>1)&3); stage source granule (lane&3)^((lane>>3)&3)
// (row>>1 parity: both sides reduce to the same involution, verified).
// ============================================================================
template<int OUT_BF16>
__global__ __launch_bounds__(512, 2) void gemm2_k(const short* __restrict__ A,
    const short* __restrict__ Bt, void* __restrict__ Cv,
    const float* __restrict__ bias,
    int K, int lda, int ldb, int ldc,
    long long sA, long long sB, long long sC, long long sBias,
    float scale, int gxs, int gys)
{
  __shared__ __align__(16) short lds[3][16384];  // per buf: A [0,8192) B [8192,16384)
  XCD_DECODE(gxs, gys);
  A  += (long long)z * sA;
  Bt += (long long)z * sB;
  const int bm = byi * 256;
  const int bn = bxi * 256;
  const int tid  = threadIdx.x;
  const int w    = tid >> 6, lane = tid & 63;
  const int wr   = w >> 2,   wc   = w & 3;     // per-wave 128(M) x 64(N)
  const int lr   = lane & 15, lk  = lane >> 4;

  const int rsw  = (lk ^ ((lr >> 1) & 3)) * 8;           // read granule (shorts)
  const int srow = w * 16 + (lane >> 2);                 // 0..127 within region
  const int sg   = ((lane & 3) ^ ((lane >> 3) & 3)) * 8; // stage source granule
  const short* gA[2]; const short* gB[2];
  #pragma unroll
  for (int i = 0; i < 2; ++i) {
    gA[i] = A  + (long long)(bm + i*128 + srow) * lda + sg;
    gB[i] = Bt + (long long)(bn + i*128 + srow) * ldb + sg;
  }

  #define STGA2(buf, i, kt) \
    __builtin_amdgcn_global_load_lds((gas1_t)(gA[i] + (long long)(kt)*32), \
        (las3_t)&lds[buf][(i)*4096 + w*512], 16, 0, 0)
  #define STGB2(buf, i, kt) \
    __builtin_amdgcn_global_load_lds((gas1_t)(gB[i] + (long long)(kt)*32), \
        (las3_t)&lds[buf][8192 + (i)*4096 + w*512], 16, 0, 0)
  #define RDA2(buf, mi) (*(const short8*)&lds[buf][(wr*128 + (mi)*16 + lr)*32 + rsw])
  #define RDB2(buf, ni) (*(const short8*)&lds[buf][8192 + (wc*64 + (ni)*16 + lr)*32 + rsw])

  f32x4 acc[8][4] = {};
  const int nt = K >> 5;

  // prologue: tile0 -> buf0, tile1 -> buf1; drain tile0 (vmcnt(4))
  STGA2(0, 0, 0); STGA2(0, 1, 0); STGB2(0, 0, 0); STGB2(0, 1, 0);
  STGA2(1, 0, 1); STGA2(1, 1, 1); STGB2(1, 0, 1); STGB2(1, 1, 1);
  asm volatile("s_waitcnt vmcnt(4)" ::: "memory");
  __builtin_amdgcn_s_barrier();

  int b = 0, nb = 2;
  for (int g = 0; g < nt; ++g) {
    short8 aR[4], bR[4];
    // ---- half 1: mi 0-3 ----
    #pragma unroll
    for (int mi = 0; mi < 4; ++mi) aR[mi] = RDA2(b, mi);
    #pragma unroll
    for (int ni = 0; ni < 4; ++ni) bR[ni] = RDB2(b, ni);
    if (g + 2 < nt) { STGA2(nb, 0, g+2); STGA2(nb, 1, g+2); }
    LGKM0;
    __builtin_amdgcn_s_setprio(1);
    #pragma unroll
    for (int mi = 0; mi < 4; ++mi)
      #pragma unroll
      for (int ni = 0; ni < 4; ++ni)
        MFMA16(acc[mi][ni], aR[mi], bR[ni]);
    __builtin_amdgcn_s_setprio(0);
    // ---- half 2: mi 4-7 (bR reused) ----
    #pragma unroll
    for (int mi = 0; mi < 4; ++mi) aR[mi] = RDA2(b, mi + 4);
    if (g + 2 < nt) { STGB2(nb, 0, g+2); STGB2(nb, 1, g+2); }
    LGKM0;
    __builtin_amdgcn_s_setprio(1);
    #pragma unroll
    for (int mi = 0; mi < 4; ++mi)
      #pragma unroll
      for (int ni = 0; ni < 4; ++ni)
        MFMA16(acc[mi+4][ni], aR[mi], bR[ni]);
    __builtin_amdgcn_s_setprio(0);
    if (g + 2 < nt)      asm volatile("s_waitcnt vmcnt(4)" ::: "memory");
    else if (g + 1 < nt) asm volatile("s_waitcnt vmcnt(0)" ::: "memory");
    __builtin_amdgcn_s_barrier();
    b  = (b  == 2) ? 0 : b  + 1;
    nb = (nb == 2) ? 0 : nb + 1;
  }

  const float* bz = bias ? (bias + (long long)z * sBias) : nullptr;
  #pragma unroll
  for (int mi = 0; mi < 8; ++mi) {
    const int row = bm + wr*128 + mi*16 + (lane >> 4)*4;
    #pragma unroll
    for (int ni = 0; ni < 4; ++ni) {
      const int col = bn + wc*64 + ni*16 + lr;
      const float bval = bz ? bz[col] : 0.f;
      #pragma unroll
      for (int r = 0; r < 4; ++r) {
        float val = acc[mi][ni][r] * scale + bval;
        if (OUT_BF16)
          ((short*)Cv)[(long long)z*sC + (long long)(row + r) * ldc + col] = f2bf(val);
        else
          ((float*)Cv)[(long long)z*sC + (long long)(row + r) * ldc + col] = val;
      }
    }
  }
  #undef STGA2
  #undef STGB2
  #undef RDA2
  #undef RDB2
}

// ============================================================================
// 256x128 GEMM, BK=64, 3-buffer ring, 1 barrier/tile, 16x16x32 MFMA,
// wave layout (4,2) per-wave 64x64 — the R4-proven conflict-free template.
// ============================================================================
template<int OUT_BF16, int BIAS_ROW>
__global__ __launch_bounds__(512, 2) void gemm4_k(const short* __restrict__ A,
    const short* __restrict__ Bt, void* __restrict__ Cv,
    const float* __restrict__ bias,
    int K, int lda, int ldb, int ldc,
    long long sA, long long sB, long long sC, long long sBias,
    float scale, int gxs, int gys)
{
  __shared__ __align__(16) short lds[3][24576];  // per buf: A [0,16384) B [16384,24576)
  XCD_DECODE(gxs, gys);
  A  += (long long)z * sA;
  Bt += (long long)z * sB;
  const int bm = byi * 256;
  const int bn = bxi * 128;
  const int tid  = threadIdx.x;
  const int w    = tid >> 6, lane = tid & 63;
  const int wr   = w >> 1,   wc   = w & 1;     // (WM,WN) = (4,2)
  const int lr   = lane & 15, lk  = lane >> 4;

  const int rsw0 = ((lk    ) ^ (lr & 7)) * 8;
  const int rsw1 = ((lk + 4) ^ (lr & 7)) * 8;
  const int srow = w * 8 + (lane >> 3);
  const int swc  = ((lane & 7) ^ ((lane >> 3) & 7)) * 8;
  const short* gA[4]; const short* gB[2];
  #pragma unroll
  for (int i = 0; i < 4; ++i)
    gA[i] = A + (long long)(bm + i*64 + srow) * lda + swc;
  #pragma unroll
  for (int i = 0; i < 2; ++i)
    gB[i] = Bt + (long long)(bn + i*64 + srow) * ldb + swc;

  #define STGA(buf, i, kt) \
    __builtin_amdgcn_global_load_lds((gas1_t)(gA[i] + (long long)(kt)*64), \
        (las3_t)&lds[buf][(i)*4096 + w*512], 16, 0, 0)
  #define STGB(buf, i, kt) \
    __builtin_amdgcn_global_load_lds((gas1_t)(gB[i] + (long long)(kt)*64), \
        (las3_t)&lds[buf][16384 + (i)*4096 + w*512], 16, 0, 0)
  #define RDA4(buf, mi, ks) (*(const short8*)&lds[buf][(wr*64 + (mi)*16 + lr)*64 + ((ks) ? rsw1 : rsw0)])
  #define RDB4(buf, ni, ks) (*(const short8*)&lds[buf][16384 + (wc*64 + (ni)*16 + lr)*64 + ((ks) ? rsw1 : rsw0)])

  f32x4 acc[4][4] = {};
  const int nt = K >> 6;

  STGA(0, 0, 0); STGA(0, 2, 0); STGB(0, 0, 0);
  STGB(0, 1, 0); STGA(0, 1, 0); STGA(0, 3, 0);
  STGA(1, 0, 1); STGA(1, 2, 1); STGB(1, 0, 1);
  STGB(1, 1, 1); STGA(1, 1, 1); STGA(1, 3, 1);
  asm volatile("s_waitcnt vmcnt(6)" ::: "memory");
  __builtin_amdgcn_s_barrier();

  int b = 0, nb = 2;
  for (int g = 0; g < nt; ++g) {
    short8 aR[4], bR[4];
    // ---- half 1: ks = 0 ----
    #pragma unroll
    for (int mi = 0; mi < 4; ++mi) aR[mi] = RDA4(b, mi, 0);
    #pragma unroll
    for (int ni = 0; ni < 4; ++ni) bR[ni] = RDB4(b, ni, 0);
    if (g + 2 < nt) { STGA(nb, 0, g+2); STGA(nb, 2, g+2); STGB(nb, 0, g+2); }
    LGKM0;
    __builtin_amdgcn_s_setprio(1);
    #pragma unroll
    for (int mi = 0; mi < 4; ++mi)
      #pragma unroll
      for (int ni = 0; ni < 4; ++ni)
        MFMA16(acc[mi][ni], aR[mi], bR[ni]);
    __builtin_amdgcn_s_setprio(0);
    // ---- half 2: ks = 1 ----
    #pragma unroll
    for (int mi = 0; mi < 4; ++mi) aR[mi] = RDA4(b, mi, 1);
    #pragma unroll
    for (int ni = 0; ni < 4; ++ni) bR[ni] = RDB4(b, ni, 1);
    if (g + 2 < nt) { STGB(nb, 1, g+2); STGA(nb, 1, g+2); STGA(nb, 3, g+2); }
    LGKM0;
    __builtin_amdgcn_s_setprio(1);
    #pragma unroll
    for (int mi = 0; mi < 4; ++mi)
      #pragma unroll
      for (int ni = 0; ni < 4; ++ni)
        MFMA16(acc[mi][ni], aR[mi], bR[ni]);
    __builtin_amdgcn_s_setprio(0);
    if (g + 2 < nt)      asm volatile("s_waitcnt vmcnt(6)" ::: "memory");
    else if (g + 1 < nt) asm volatile("s_waitcnt vmcnt(0)" ::: "memory");
    __builtin_amdgcn_s_barrier();
    b  = (b  == 2) ? 0 : b  + 1;
    nb = (nb == 2) ? 0 : nb + 1;
  }

  const float* bz = bias;
  #pragma unroll
  for (int mi = 0; mi < 4; ++mi) {
    const int row = bm + wr*64 + mi*16 + lk*4;
    #pragma unroll
    for (int ni = 0; ni < 4; ++ni) {
      const int col = bn + wc*64 + ni*16 + lr;
      const float bcol = (bz && !BIAS_ROW) ? bz[(long long)z*sBias + col] : 0.f;
      #pragma unroll
      for (int r = 0; r < 4; ++r) {
        float bval = BIAS_ROW ? bz[row + r] : bcol;
        float val = acc[mi][ni][r] * scale + bval;
        if (OUT_BF16)
          ((short*)Cv)[(long long)z*sC + (long long)(row + r) * ldc + col] = f2bf(val);
        else
          ((float*)Cv)[(long long)z*sC + (long long)(row + r) * ldc + col] = val;
      }
    }
  }
  #undef STGA
  #undef STGB
  #undef RDA4
  #undef RDB4
}

extern "C" void kernel_launch(void* const* d_in, const int* in_sizes, int n_in,
                              void* d_out, int out_size, void* d_ws, size_t ws_size,
                              hipStream_t stream) {
  const float* q  = (const float*)d_in[0];
  const float* k  = (const float*)d_in[1];
  const float* v  = (const float*)d_in[2];
  const float* Wq = (const float*)d_in[4];
  const float* bq = (const float*)d_in[5];
  const float* Wk = (const float*)d_in[6];
  const float* bk = (const float*)d_in[7];
  const float* Wv = (const float*)d_in[8];
  const float* bv = (const float*)d_in[9];
  const float* Wo = (const float*)d_in[10];
  const float* bo = (const float*)d_in[11];

  // ws layout (bytes):
  char* w = (char*)d_ws;
  short* Wt     = (short*)(w);                  // [4][1024][1024] bf16 (W^T)   8,388,608
  float* biasb  = (float*)(w + 8388608);        // [4][1024] f32                   16,384
  short* QKV    = (short*)(w + 8404992);        // Q,K bf16 [2][4,2048,1024]
  short* qkvbf  = (short*)(w + 58736640);       // q,k,v bf16, die after projections
  short* P      = (short*)(w + 58736640);       // scores/P bf16 [4,2048,2048] (reuses q,k part)
  short* Vt     = (short*)(w + 109068288);      // [1024][8192] bf16            16,777,216
  short* xt     = (short*)(w + 125845504);      // [4][1024][2048] bf16         16,777,216

  short* Qp = QKV;
  short* Kp = QKV + 8388608LL;
  short* vbf = qkvbf + 16777216LL;              // outside P's live range

  // 1) convert inputs + weights, gather biases
  cvt_qkv_k<<<dim3(4096,1,3), 256, 0, stream>>>(q, k, v, qkvbf);
  bias_gather_k<<<dim3(16), 256, 0, stream>>>(bq, bk, bv, bo, biasb);
  wt_cvt_k<<<dim3(32,32,4), dim3(32,8), 0, stream>>>(Wq, Wk, Wv, Wo, Wt);

  // 2a) q,k projections via gemm2: 4(N) x 32(M) x 2(z) = 256 blocks
  gemm2_k<1><<<256, 512, 0, stream>>>(qkvbf, Wt, QKV, biasb,
      1024, 1024, 1024, 1024, 8388608LL, 1048576LL, 8388608LL, 1024LL, 1.0f, 2, 5);

  // 2b) V projection, transposed output: Vt[d, bs] = Wv^T @ v_bf^T + bv[d]
  gemm4_k<1,1><<<256, 512, 0, stream>>>(Wt + 2097152LL, vbf, Vt, biasb + 2048,
      1024, 1024, 1024, 8192, 0LL, 0LL, 0LL, 0LL, 1.0f, 6, 2);

  // 3) scores = Q @ K^T / 32 -> bf16 P via gemm2: 8(N) x 8(M) x 4(z) = 256
  gemm2_k<1><<<256, 512, 0, stream>>>(Qp, Kp, P, nullptr,
      1024, 1024, 1024, 2048, 2097152LL, 2097152LL, 4194304LL, 0LL, 0.03125f, 3, 3);

  // 4) P = softmax_rows(P) in place
  softmax_bf_k<<<dim3(8192), 256, 0, stream>>>(P);

  // 5) xt[d, q] = Vt[d,:] . P[q,:]  (A = Vt + z*2048 cols, lda=8192)
  gemm4_k<1,0><<<256, 512, 0, stream>>>(Vt, P, xt, nullptr,
      2048, 8192, 2048, 2048, 2048LL, 4194304LL, 2097152LL, 0LL, 1.0f, 4, 2);

  // 6) out = reshape(xt) @ Wo + bo; xt reinterpreted [2048][1024] row-major per z
  gemm4_k<0,0><<<256, 512, 0, stream>>>(xt, Wt + 3145728LL, (float*)d_out,
      biasb + 3072, 1024, 1024, 1024, 1024, 2097152LL, 0LL, 2097152LL, 0LL, 1.0f, 3, 3);
}